// Round 1
// baseline (317.157 us; speedup 1.0000x reference)
//
#include <hip/hip_runtime.h>
#include <hip/hip_bf16.h>

// Problem constants (B,C,H,W)=(4,64,64,64) -> N=4096, Cr=8
#define BB 4
#define CC 64
#define NN 4096
#define CR 8

#define SPLIT 8            // key chunks (split-K over keys)
#define KC (NN / SPLIT)    // 512 keys per chunk
#define TK 32              // keys per LDS tile
#define QB 256             // queries per block

// workspace layout (float offsets)
#define Q_OFF 0
#define K_OFF (BB * NN * CR)                   // 131072
#define V_OFF (2 * BB * NN * CR)               // 262144
#define PACC_OFF (V_OFF + BB * NN * CC)        // 1310720
#define PL_OFF (PACC_OFF + SPLIT * BB * NN * CC) // 9699328
// total floats = PL_OFF + SPLIT*BB*NN = 9830400 -> 37.5 MB workspace

// ---------------------------------------------------------------------------
// Kernel 1: QKV projection (1x1 conv == per-pixel matvec over channels)
// q_ws[b][n][o] = bq[o] + sum_c wq[o][c] x[b][c][n]   (o<8)
// k_ws[b][n][o] = bk[o] + sum_c wk[o][c] x[b][c][n]   (o<8)
// v_ws[b][m][c] = bv[c] + sum_cc wv[c][cc] x[b][cc][m]
// ---------------------------------------------------------------------------
__global__ __launch_bounds__(64) void qkv_kernel(
    const float* __restrict__ x,
    const float* __restrict__ wq, const float* __restrict__ bq,
    const float* __restrict__ wk, const float* __restrict__ bk,
    const float* __restrict__ wv, const float* __restrict__ bv,
    float* __restrict__ ws)
{
    const int t  = threadIdx.x;
    const int ng = blockIdx.x * 64 + t;      // global (b,n) flat
    const int b  = ng >> 12;                 // / 4096
    const int n  = ng & (NN - 1);

    float xr[CC];
#pragma unroll
    for (int c = 0; c < CC; ++c)
        xr[c] = x[(b * CC + c) * NN + n];    // coalesced over t

    float* qw = ws + Q_OFF;
    float* kw = ws + K_OFF;
    float* vw = ws + V_OFF;

#pragma unroll
    for (int o = 0; o < CR; ++o) {
        float sq = bq[o];
        float sk = bk[o];
#pragma unroll
        for (int c = 0; c < CC; ++c) {
            sq += wq[o * CC + c] * xr[c];    // uniform -> scalar loads
            sk += wk[o * CC + c] * xr[c];
        }
        qw[(b * NN + n) * CR + o] = sq;
        kw[(b * NN + n) * CR + o] = sk;
    }

#pragma unroll 8
    for (int o = 0; o < CC; ++o) {
        float sv = bv[o];
#pragma unroll
        for (int c = 0; c < CC; ++c)
            sv += wv[o * CC + c] * xr[c];
        vw[(b * NN + n) * CC + o] = sv;
    }
}

// ---------------------------------------------------------------------------
// Kernel 2: flash attention partials over one key chunk.
// No running max: logits are bounded (|logit| << 80), raw exp is safe in fp32.
// Per block: batch b, 256 queries, keys [s*KC, (s+1)*KC).
// Per 32-key tile: phase1 (lane-per-query) writes exp'd P tile to LDS
// (transposed [m][q]); phase2 (lane owns 4 queries x 16 channels) accumulates
// P*V with 4x V-register reuse.
// ---------------------------------------------------------------------------
__global__ __launch_bounds__(256) void attn_kernel(float* __restrict__ ws)
{
    const float* qw   = ws + Q_OFF;
    const float* kw   = ws + K_OFF;
    const float* vw   = ws + V_OFF;
    float*       pacc = ws + PACC_OFF;
    float*       pl   = ws + PL_OFF;

    __shared__ float k_t[TK * CR];     // 1 KB
    __shared__ float v_t[TK * CC];     // 8 KB
    __shared__ float p_t[TK * QB];     // 32 KB, layout [m][q] (conflict-free)

    const int tid  = threadIdx.x;
    const int w    = tid >> 6;
    const int lane = tid & 63;
    const int qg   = lane & 15;        // phase-2 query group
    const int cp   = lane >> 4;        // phase-2 channel part

    const int b      = blockIdx.y;
    const int q_base = blockIdx.x * QB;
    const int s      = blockIdx.z;
    const int m_base = s * KC;

    // phase-1: this thread owns query q1 entirely (for logits and l-sum)
    const int q1 = q_base + tid;
    const float4 qv0 = *(const float4*)&qw[(b * NN + q1) * CR + 0];
    const float4 qv1 = *(const float4*)&qw[(b * NN + q1) * CR + 4];
    float lsum = 0.f;

    // phase-2: 4 queries x 16 channels accumulators
    const int q2 = w * 64 + qg * 4;    // local query base (0..255)
    const int c0 = cp * 16;
    float acc[4][16];
#pragma unroll
    for (int i = 0; i < 4; ++i)
#pragma unroll
        for (int j = 0; j < 16; ++j) acc[i][j] = 0.f;

    for (int kt = 0; kt < KC; kt += TK) {
        const int m0 = m_base + kt;

        // cooperative load of K tile (256 floats) and V tile (2048 floats)
        k_t[tid] = kw[(b * NN + m0) * CR + tid];
        {
            const float4* src = (const float4*)&vw[(size_t)(b * NN + m0) * CC];
            float4* dst = (float4*)v_t;
            dst[tid]       = src[tid];
            dst[tid + 256] = src[tid + 256];
        }
        __syncthreads();

        // phase 1: logits + exp for my query over all TK keys
#pragma unroll 8
        for (int m = 0; m < TK; ++m) {
            const float4 ka = *(const float4*)&k_t[m * CR + 0];
            const float4 kb = *(const float4*)&k_t[m * CR + 4];
            float lg = qv0.x * ka.x + qv0.y * ka.y + qv0.z * ka.z + qv0.w * ka.w
                     + qv1.x * kb.x + qv1.y * kb.y + qv1.z * kb.z + qv1.w * kb.w;
            float p = __expf(lg);
            p_t[m * QB + tid] = p;     // consecutive lanes -> consecutive addrs
            lsum += p;
        }
        __syncthreads();

        // phase 2: acc[q][c] += p[q][m] * v[m][c]
#pragma unroll 4
        for (int m = 0; m < TK; ++m) {
            const float4 pv = *(const float4*)&p_t[m * QB + q2];
            float vv[16];
#pragma unroll
            for (int j = 0; j < 4; ++j) {
                const float4 t4 = *(const float4*)&v_t[m * CC + c0 + 4 * j];
                vv[4 * j + 0] = t4.x; vv[4 * j + 1] = t4.y;
                vv[4 * j + 2] = t4.z; vv[4 * j + 3] = t4.w;
            }
            const float pq[4] = {pv.x, pv.y, pv.z, pv.w};
#pragma unroll
            for (int qq = 0; qq < 4; ++qq)
#pragma unroll
                for (int j = 0; j < 16; ++j)
                    acc[qq][j] += pq[qq] * vv[j];
        }
        __syncthreads();
    }

    // epilogue: store partial l (phase-1 query) and partial acc (phase-2 set)
    pl[(size_t)(s * BB + b) * NN + q1] = lsum;

#pragma unroll
    for (int qq = 0; qq < 4; ++qq) {
        const int qglob = q_base + q2 + qq;
        float* dstp = &pacc[((size_t)(s * BB + b) * NN + qglob) * CC + c0];
#pragma unroll
        for (int j = 0; j < 4; ++j) {
            ((float4*)dstp)[j] = make_float4(acc[qq][4 * j + 0], acc[qq][4 * j + 1],
                                             acc[qq][4 * j + 2], acc[qq][4 * j + 3]);
        }
    }
}

// ---------------------------------------------------------------------------
// Kernel 3: combine split-K partials, softmax divide, residual + gamma
// out[b][c][n] = x[b][c][n] + gamma * (sum_s acc_s[b][n][c]) / (sum_s l_s[b][n])
// ---------------------------------------------------------------------------
__global__ __launch_bounds__(256) void combine_kernel(
    const float* __restrict__ x, const float* __restrict__ gamma,
    const float* __restrict__ ws, float* __restrict__ out)
{
    const int idx = blockIdx.x * 256 + threadIdx.x;  // (b*CC + c)*NN + n
    const int n  = idx & (NN - 1);
    const int bc = idx >> 12;
    const int c  = bc & (CC - 1);
    const int b  = bc >> 6;

    const float* pacc = ws + PACC_OFF;
    const float* pl   = ws + PL_OFF;

    float num = 0.f, den = 0.f;
#pragma unroll
    for (int s = 0; s < SPLIT; ++s) {
        num += pacc[((size_t)(s * BB + b) * NN + n) * CC + c];
        den += pl[(size_t)(s * BB + b) * NN + n];
    }
    out[idx] = x[idx] + gamma[0] * (num / den);
}

// ---------------------------------------------------------------------------
extern "C" void kernel_launch(void* const* d_in, const int* in_sizes, int n_in,
                              void* d_out, int out_size, void* d_ws, size_t ws_size,
                              hipStream_t stream)
{
    const float* x     = (const float*)d_in[0];
    const float* wq    = (const float*)d_in[1];
    const float* bq    = (const float*)d_in[2];
    const float* wk    = (const float*)d_in[3];
    const float* bk    = (const float*)d_in[4];
    const float* wv    = (const float*)d_in[5];
    const float* bv    = (const float*)d_in[6];
    const float* gamma = (const float*)d_in[7];
    float* ws  = (float*)d_ws;
    float* out = (float*)d_out;

    hipLaunchKernelGGL(qkv_kernel, dim3(BB * NN / 64), dim3(64), 0, stream,
                       x, wq, bq, wk, bk, wv, bv, ws);
    hipLaunchKernelGGL(attn_kernel, dim3(NN / QB, BB, SPLIT), dim3(256), 0, stream, ws);
    hipLaunchKernelGGL(combine_kernel, dim3(BB * CC * NN / 256), dim3(256), 0, stream,
                       x, gamma, ws, out);
}

// Round 2
// 129.119 us; speedup vs baseline: 2.4563x; 2.4563x over previous
//
#include <hip/hip_runtime.h>

// (B,C,H,W) = (4,64,64,64) -> N=4096, Cr=8. Single-head attn, d_k=8, d_v=64.
#define BB 4
#define CC 64
#define NN 4096

typedef __attribute__((ext_vector_type(8))) short short8;
typedef __attribute__((ext_vector_type(4))) float f32x4;
typedef unsigned short u16;

// workspace byte layout (all bf16):
//   qws [B*N][8], kws [B*N][8], vws [B*64][N]  (V transposed: channel-major)
#define QWS_ELEMS (BB * NN * 8)

__device__ inline u16 f2bf(float x) {
    unsigned u = __float_as_uint(x);
    u = (u + 0x7fffu + ((u >> 16) & 1u)) >> 16;   // RNE
    return (u16)u;
}
__device__ inline unsigned pack2(float a, float b) {
    return (unsigned)f2bf(a) | ((unsigned)f2bf(b) << 16);
}

// ---------------------------------------------------------------------------
// Kernel 1: QKV projection, fp32 -> bf16. 4 channel-groups per pixel.
// thread (pixel, g): q/k channels {2g,2g+1}, v channels [16g,16g+16).
// ---------------------------------------------------------------------------
__global__ __launch_bounds__(256) void proj_kernel(
    const float* __restrict__ x,
    const float* __restrict__ wq, const float* __restrict__ bq,
    const float* __restrict__ wk, const float* __restrict__ bk,
    const float* __restrict__ wv, const float* __restrict__ bv,
    u16* __restrict__ ws_u)
{
    u16* qws = ws_u;
    u16* kws = ws_u + QWS_ELEMS;
    u16* vws = ws_u + 2 * QWS_ELEMS;

    const int tid = threadIdx.x;
    const int g   = tid >> 6;                       // wave-uniform group
    const int pix = (blockIdx.x << 6) + (tid & 63); // (b,n) flat
    const int b   = pix >> 12;
    const int n   = pix & (NN - 1);

    float xr[CC];
#pragma unroll
    for (int c = 0; c < CC; ++c)
        xr[c] = x[((size_t)((b << 6) + c) << 12) + n];   // coalesced

    float sq[2], sk[2];
#pragma unroll
    for (int oc = 0; oc < 2; ++oc) {
        const int o = (g << 1) + oc;
        float a = bq[o], kk = bk[o];
#pragma unroll
        for (int c = 0; c < CC; ++c) {
            a  += wq[o * CC + c] * xr[c];   // uniform -> scalar loads
            kk += wk[o * CC + c] * xr[c];
        }
        sq[oc] = a; sk[oc] = kk;
    }
    *(unsigned*)&qws[(size_t)pix * 8 + (g << 1)] = pack2(sq[0], sq[1]);
    *(unsigned*)&kws[(size_t)pix * 8 + (g << 1)] = pack2(sk[0], sk[1]);

#pragma unroll 4
    for (int vi = 0; vi < 16; ++vi) {
        const int o = (g << 4) + vi;
        float s = bv[o];
#pragma unroll
        for (int c = 0; c < CC; ++c)
            s += wv[o * CC + c] * xr[c];
        vws[((size_t)((b << 6) + o) << 12) + n] = f2bf(s);  // transposed store
    }
}

// ---------------------------------------------------------------------------
// Kernel 2: fused MFMA flash attention + softmax divide + residual.
// Block: 256 thr (4 waves), batch b, 32 queries. Wave w: (wqc=w&1 -> q-chunk,
// wh=w>>1 -> m-chunk for S / c-half for PV). 32-key tiles, double-buffered
// LDS, ONE barrier per tile. S computed transposed (Sᵀ = K·Qᵀ) so the
// C-fragment packs into b64 LDS writes and reads back as contiguous A-frags.
// No running max: |logit| <= ~16 so raw exp is safe in fp32/bf16.
// ---------------------------------------------------------------------------
__global__ __launch_bounds__(256) void attn_kernel(
    const float* __restrict__ x, const float* __restrict__ gamma,
    const u16* __restrict__ ws_u, float* __restrict__ out)
{
    const u16* qws = ws_u;
    const u16* kws = ws_u + QWS_ELEMS;
    const u16* vws = ws_u + 2 * QWS_ELEMS;

    __shared__ u16   v_t[2][CC * 36];   // [c][32m], rows padded to 72 B
    __shared__ u16   p_t[2][32 * 36];   // [q][32m], rows padded to 72 B
    __shared__ float l_sh[2][32];       // per-m-chunk row sums

    const int tid  = threadIdx.x;
    const int w    = tid >> 6;
    const int lane = tid & 63;
    const int quad = lane >> 4;
    const int l15  = lane & 15;
    const int wqc  = w & 1;
    const int wh   = w >> 1;

    const int b  = blockIdx.y;
    const int qb = blockIdx.x << 5;    // 32 queries/block
    const int bN = b << 12;

    // Q B-frag: B[k=c][n=q], quad0 holds c=0..7 (real), quads 1-3 zero.
    short8 qf = {0, 0, 0, 0, 0, 0, 0, 0};
    if (quad == 0)
        qf = *(const short8*)(qws + (size_t)(bN + qb + (wqc << 4) + l15) * 8);

    // K A-frag prefetch (tile 0): A[m][k=c], quads 1-3 stay zero forever.
    short8 kf = {0, 0, 0, 0, 0, 0, 0, 0};
    if (quad == 0)
        kf = *(const short8*)(kws + (size_t)(bN + (wh << 4) + l15) * 8);

    // V staging: thread -> (c_row, 8-key chunk); prefetch tile 0.
    const int c_row = tid >> 2;
    const int mo    = (tid & 3) << 3;
    const u16* vrow = vws + ((size_t)((b << 6) + c_row) << 12);
    short8 vpre = *(const short8*)(vrow + mo);

    const int vt_off = c_row * 36 + mo;
    const int pw_off = ((wqc << 4) + l15) * 36 + (wh << 4) + (quad << 2);
    const int pr_off = ((wqc << 4) + l15) * 36 + (quad << 3);
    const int v0_off = ((wh << 5) + l15) * 36 + (quad << 3);
    const int v1_off = ((wh << 5) + 16 + l15) * 36 + (quad << 3);

    f32x4 acc0 = {0.f, 0.f, 0.f, 0.f};
    f32x4 acc1 = {0.f, 0.f, 0.f, 0.f};
    float lsum = 0.f;

    for (int it = 0; it < 128; ++it) {
        const int buf   = it & 1;
        const int mnext = ((it + 1) & 127) << 5;   // wrap: harmless warm read

        // stage current V tile, then prefetch next (overlaps all compute)
        *(short8*)&v_t[buf][vt_off] = vpre;
        vpre = *(const short8*)(vrow + mnext + mo);

        // Sᵀ tile: D[m][q] = K·Qᵀ  (no LDS dependency -> before barrier)
        f32x4 s = __builtin_amdgcn_mfma_f32_16x16x32_bf16(
            kf, qf, (f32x4){0.f, 0.f, 0.f, 0.f}, 0, 0, 0);
        if (quad == 0)   // prefetch next K A-frag after use
            kf = *(const short8*)(kws + (size_t)(bN + mnext + (wh << 4) + l15) * 8);

        const float p0 = __expf(s[0]), p1 = __expf(s[1]);
        const float p2 = __expf(s[2]), p3 = __expf(s[3]);
        lsum += (p0 + p1) + (p2 + p3);
        uint2 pw; pw.x = pack2(p0, p1); pw.y = pack2(p2, p3);
        *(uint2*)&p_t[buf][pw_off] = pw;   // 4 consecutive m -> one b64

        __syncthreads();   // v_t & p_t[buf] ready; dbuf makes this the only barrier

        const short8 pf  = *(const short8*)&p_t[buf][pr_off];
        const short8 vf0 = *(const short8*)&v_t[buf][v0_off];
        const short8 vf1 = *(const short8*)&v_t[buf][v1_off];
        acc0 = __builtin_amdgcn_mfma_f32_16x16x32_bf16(pf, vf0, acc0, 0, 0, 0);
        acc1 = __builtin_amdgcn_mfma_f32_16x16x32_bf16(pf, vf1, acc1, 0, 0, 0);
    }

    // full softmax denominator: reduce quads (disjoint m), then m-chunk waves
    lsum += __shfl_xor(lsum, 16, 64);
    lsum += __shfl_xor(lsum, 32, 64);
    if (quad == 0) l_sh[wh][(wqc << 4) + l15] = lsum;
    __syncthreads();

    const int q0 = (wqc << 4) + (quad << 2);   // local q of acc rows
    float rl[4];
#pragma unroll
    for (int r = 0; r < 4; ++r)
        rl[r] = 1.f / (l_sh[0][q0 + r] + l_sh[1][q0 + r]);

    const float g = gamma[0];
#pragma unroll
    for (int ch = 0; ch < 2; ++ch) {
        const int c = (wh << 5) + (ch << 4) + l15;
        const size_t base = ((size_t)((b << 6) + c) << 12) + qb + q0;
        const float4 xv = *(const float4*)&x[base];
        const f32x4 a = ch ? acc1 : acc0;
        float4 o;
        o.x = xv.x + g * a[0] * rl[0];
        o.y = xv.y + g * a[1] * rl[1];
        o.z = xv.z + g * a[2] * rl[2];
        o.w = xv.w + g * a[3] * rl[3];
        *(float4*)&out[base] = o;
    }
}

// ---------------------------------------------------------------------------
extern "C" void kernel_launch(void* const* d_in, const int* in_sizes, int n_in,
                              void* d_out, int out_size, void* d_ws, size_t ws_size,
                              hipStream_t stream)
{
    const float* x     = (const float*)d_in[0];
    const float* wq    = (const float*)d_in[1];
    const float* bq    = (const float*)d_in[2];
    const float* wk    = (const float*)d_in[3];
    const float* bk    = (const float*)d_in[4];
    const float* wv    = (const float*)d_in[5];
    const float* bv    = (const float*)d_in[6];
    const float* gamma = (const float*)d_in[7];
    u16*   ws  = (u16*)d_ws;
    float* out = (float*)d_out;

    hipLaunchKernelGGL(proj_kernel, dim3(BB * NN / 64), dim3(256), 0, stream,
                       x, wq, bq, wk, bk, wv, bv, ws);
    hipLaunchKernelGGL(attn_kernel, dim3(NN / 32, BB), dim3(256), 0, stream,
                       x, gamma, ws, out);
}

// Round 3
// 112.299 us; speedup vs baseline: 2.8242x; 1.1498x over previous
//
#include <hip/hip_runtime.h>

// (B,C,H,W) = (4,64,64,64) -> N=4096, Cr=8. Single-head attn, d_k=8, d_v=64.
#define BB 4
#define CC 64
#define NN 4096

typedef __attribute__((ext_vector_type(8))) short short8;
typedef __attribute__((ext_vector_type(4))) float f32x4;
typedef unsigned short u16;

// workspace (all bf16): qws [B*N][8], kws [B*N][8], vws [B*64][N] (V transposed)
#define QWS_ELEMS (BB * NN * 8)

__device__ inline u16 f2bf(float x) {
    unsigned u = __float_as_uint(x);
    u = (u + 0x7fffu + ((u >> 16) & 1u)) >> 16;   // RNE
    return (u16)u;
}

// pack2 high-halves (truncating bf16 convert) in ONE v_perm_b32:
// result = (bf_trunc(hi) << 16) | bf_trunc(lo)
__device__ inline unsigned permpack(float lo, float hi) {
    return __builtin_amdgcn_perm(__float_as_uint(hi), __float_as_uint(lo), 0x07060302);
}

// ---------------------------------------------------------------------------
// Kernel 1: QKV projection. blockIdx.y = unit u (UNIFORM -> scalar weight
// loads). Unit u computes q[u], k[u], v[8u..8u+8] for 256 pixels.
// ---------------------------------------------------------------------------
__global__ __launch_bounds__(256) void proj_kernel(
    const float* __restrict__ x,
    const float* __restrict__ wq, const float* __restrict__ bq,
    const float* __restrict__ wk, const float* __restrict__ bk,
    const float* __restrict__ wv, const float* __restrict__ bv,
    u16* __restrict__ ws_u)
{
    u16* qws = ws_u;
    u16* kws = ws_u + QWS_ELEMS;
    u16* vws = ws_u + 2 * QWS_ELEMS;

    const int u   = blockIdx.y;                       // 0..7, wave-uniform
    const int pix = blockIdx.x * 256 + threadIdx.x;   // (b,n) flat
    const int b   = pix >> 12;
    const int n   = pix & (NN - 1);

    const float* xb = x + ((size_t)b << 18) + n;      // + c*4096 per channel

    float aq = bq[u], ak = bk[u];
    float av[8];
#pragma unroll
    for (int i = 0; i < 8; ++i) av[i] = bv[8 * u + i];

#pragma unroll 8
    for (int c = 0; c < CC; ++c) {
        const float xv = xb[(size_t)c << 12];         // coalesced 1KB/wave
        aq += wq[u * CC + c] * xv;                    // scalar (uniform) loads
        ak += wk[u * CC + c] * xv;
#pragma unroll
        for (int i = 0; i < 8; ++i)
            av[i] += wv[(8 * u + i) * CC + c] * xv;
    }

    qws[(size_t)pix * 8 + u] = f2bf(aq);
    kws[(size_t)pix * 8 + u] = f2bf(ak);
#pragma unroll
    for (int i = 0; i < 8; ++i)
        vws[(((size_t)((b << 6) + 8 * u + i)) << 12) + n] = f2bf(av[i]);
}

// ---------------------------------------------------------------------------
// Kernel 2: fused MFMA flash attention. 64-key tiles, double-buffered
// XOR-swizzled LDS, one barrier per tile. Element (row r, m) lives at
// r*64 + ((m>>3 ^ (r&7))<<3) + (m&7)  -> every b128/b64 access bank-balanced.
// Wave w: S-duty m-chunk w (16 m x 32 q); PV-duty (qc2=w&1, ch=w>>1).
// ---------------------------------------------------------------------------
__global__ __launch_bounds__(256) void attn_kernel(
    const float* __restrict__ x, const float* __restrict__ gamma,
    const u16* __restrict__ ws_u, float* __restrict__ out)
{
    const u16* qws = ws_u;
    const u16* kws = ws_u + QWS_ELEMS;
    const u16* vws = ws_u + 2 * QWS_ELEMS;

    __shared__ u16   v_t[2][CC * 64];   // swizzled [c][64m], 8 KB per buf
    __shared__ u16   p_t[2][32 * 64];   // swizzled [q][64m], 4 KB per buf
    __shared__ float l_sh[4][32];

    const int tid  = threadIdx.x;
    const int w    = tid >> 6;
    const int lane = tid & 63;
    const int quad = lane >> 4;
    const int l15  = lane & 15;

    const int b  = blockIdx.y;
    const int qb = blockIdx.x << 5;    // 32 queries/block
    const int bN = b << 12;

    // Q B-frags (quad0 holds the 8 real k=c values; other quads zero)
    short8 qf0 = {0,0,0,0,0,0,0,0}, qf1 = {0,0,0,0,0,0,0,0};
    if (quad == 0) {
        qf0 = *(const short8*)(qws + (size_t)(bN + qb + l15) * 8);
        qf1 = *(const short8*)(qws + (size_t)(bN + qb + 16 + l15) * 8);
    }

    // K A-frag prefetch for m-chunk w of tile 0
    short8 kf = {0,0,0,0,0,0,0,0};
    if (quad == 0)
        kf = *(const short8*)(kws + (size_t)(bN + (w << 4) + l15) * 8);

    // V staging: thread -> row c_row, chunks (tid&3) and (tid&3)+4
    const int c_row = tid >> 2;
    const int m4    = tid & 3;
    const u16* vrow = vws + (((size_t)((b << 6) + c_row)) << 12);
    short8 vpre0 = *(const short8*)(vrow + (m4 << 3));        // m [8*m4, +8)
    short8 vpre1 = *(const short8*)(vrow + 32 + (m4 << 3));   // m [32+8*m4, +8)

    const int sw  = c_row & 7;
    const int st0 = c_row * 64 + ((m4 ^ sw) << 3);
    const int st1 = c_row * 64 + (((m4 | 4) ^ sw) << 3);

    // P writes: m8 = 2w + (quad>>1), inner offset (quad&1)*4
    const int pm8  = (w << 1) + (quad >> 1);
    const int poff = (quad & 1) << 2;
    const int pw0  = l15 * 64        + ((pm8 ^ (l15 & 7)) << 3) + poff;
    const int pw1  = (16 + l15) * 64 + ((pm8 ^ ((16 + l15) & 7)) << 3) + poff;

    // PV fragment read offsets
    const int qc2   = w & 1;
    const int ch    = w >> 1;
    const int prow  = (qc2 << 4) + l15;
    const int crow0 = (ch << 5) + l15;
    const int crow1 = crow0 + 16;
    const int pr0 = prow * 64  + ((quad       ^ (prow & 7))  << 3);
    const int pr1 = prow * 64  + (((4 + quad) ^ (prow & 7))  << 3);
    const int v00 = crow0 * 64 + ((quad       ^ (crow0 & 7)) << 3);
    const int v01 = crow1 * 64 + ((quad       ^ (crow1 & 7)) << 3);
    const int v10 = crow0 * 64 + (((4 + quad) ^ (crow0 & 7)) << 3);
    const int v11 = crow1 * 64 + (((4 + quad) ^ (crow1 & 7)) << 3);

    f32x4 acc0 = {0.f, 0.f, 0.f, 0.f};
    f32x4 acc1 = {0.f, 0.f, 0.f, 0.f};
    float ls0 = 0.f, ls1 = 0.f;

    for (int it = 0; it < 64; ++it) {
        const int buf   = it & 1;
        const int mnext = ((it + 1) & 63) << 6;   // wrap: harmless warm read

        // stage current V tile, prefetch next
        *(short8*)&v_t[buf][st0] = vpre0;
        *(short8*)&v_t[buf][st1] = vpre1;
        vpre0 = *(const short8*)(vrow + mnext + (m4 << 3));
        vpre1 = *(const short8*)(vrow + mnext + 32 + (m4 << 3));

        // S^T tiles for m-chunk w x both q-chunks (no LDS dep -> pre-barrier)
        f32x4 s0 = __builtin_amdgcn_mfma_f32_16x16x32_bf16(
            kf, qf0, (f32x4){0.f,0.f,0.f,0.f}, 0, 0, 0);
        f32x4 s1 = __builtin_amdgcn_mfma_f32_16x16x32_bf16(
            kf, qf1, (f32x4){0.f,0.f,0.f,0.f}, 0, 0, 0);
        if (quad == 0)
            kf = *(const short8*)(kws + (size_t)(bN + mnext + (w << 4) + l15) * 8);

        const float p00 = __expf(s0[0]), p01 = __expf(s0[1]);
        const float p02 = __expf(s0[2]), p03 = __expf(s0[3]);
        const float p10 = __expf(s1[0]), p11 = __expf(s1[1]);
        const float p12 = __expf(s1[2]), p13 = __expf(s1[3]);
        ls0 += (p00 + p01) + (p02 + p03);
        ls1 += (p10 + p11) + (p12 + p13);
        uint2 a, c2;
        a.x  = permpack(p00, p01);  a.y  = permpack(p02, p03);
        c2.x = permpack(p10, p11);  c2.y = permpack(p12, p13);
        *(uint2*)&p_t[buf][pw0] = a;
        *(uint2*)&p_t[buf][pw1] = c2;

        __syncthreads();   // only barrier per 64-key tile (double-buffered)

        const short8 pf0  = *(const short8*)&p_t[buf][pr0];
        const short8 pf1  = *(const short8*)&p_t[buf][pr1];
        const short8 vf00 = *(const short8*)&v_t[buf][v00];
        const short8 vf01 = *(const short8*)&v_t[buf][v01];
        const short8 vf10 = *(const short8*)&v_t[buf][v10];
        const short8 vf11 = *(const short8*)&v_t[buf][v11];
        acc0 = __builtin_amdgcn_mfma_f32_16x16x32_bf16(pf0, vf00, acc0, 0, 0, 0);
        acc1 = __builtin_amdgcn_mfma_f32_16x16x32_bf16(pf0, vf01, acc1, 0, 0, 0);
        acc0 = __builtin_amdgcn_mfma_f32_16x16x32_bf16(pf1, vf10, acc0, 0, 0, 0);
        acc1 = __builtin_amdgcn_mfma_f32_16x16x32_bf16(pf1, vf11, acc1, 0, 0, 0);
    }

    // softmax denominator: quads hold disjoint m -> butterfly, then 4 m-chunks
    ls0 += __shfl_xor(ls0, 16, 64); ls0 += __shfl_xor(ls0, 32, 64);
    ls1 += __shfl_xor(ls1, 16, 64); ls1 += __shfl_xor(ls1, 32, 64);
    if (quad == 0) { l_sh[w][l15] = ls0; l_sh[w][16 + l15] = ls1; }
    __syncthreads();

    const int q0 = (qc2 << 4) + (quad << 2);
    float rl[4];
#pragma unroll
    for (int r = 0; r < 4; ++r)
        rl[r] = 1.f / (l_sh[0][q0 + r] + l_sh[1][q0 + r] +
                       l_sh[2][q0 + r] + l_sh[3][q0 + r]);

    const float g = gamma[0];
#pragma unroll
    for (int half = 0; half < 2; ++half) {
        const int c = half ? crow1 : crow0;
        const f32x4 acc = half ? acc1 : acc0;
        const size_t base = (((size_t)((b << 6) + c)) << 12) + qb + q0;
        const float4 xv = *(const float4*)&x[base];
        float4 o;
        o.x = xv.x + g * acc[0] * rl[0];
        o.y = xv.y + g * acc[1] * rl[1];
        o.z = xv.z + g * acc[2] * rl[2];
        o.w = xv.w + g * acc[3] * rl[3];
        *(float4*)&out[base] = o;
    }
}

// ---------------------------------------------------------------------------
extern "C" void kernel_launch(void* const* d_in, const int* in_sizes, int n_in,
                              void* d_out, int out_size, void* d_ws, size_t ws_size,
                              hipStream_t stream)
{
    const float* x     = (const float*)d_in[0];
    const float* wq    = (const float*)d_in[1];
    const float* bq    = (const float*)d_in[2];
    const float* wk    = (const float*)d_in[3];
    const float* bk    = (const float*)d_in[4];
    const float* wv    = (const float*)d_in[5];
    const float* bv    = (const float*)d_in[6];
    const float* gamma = (const float*)d_in[7];
    u16*   ws  = (u16*)d_ws;
    float* out = (float*)d_out;

    hipLaunchKernelGGL(proj_kernel, dim3(BB * NN / 256, 8), dim3(256), 0, stream,
                       x, wq, bq, wk, bk, wv, bv, ws);
    hipLaunchKernelGGL(attn_kernel, dim3(NN / 32, BB), dim3(256), 0, stream,
                       x, gamma, ws, out);
}